// Round 18
// baseline (1643.893 us; speedup 1.0000x reference)
//
#include <hip/hip_runtime.h>

// ACGI_32195074850822 — round 17: REVERT to round-15 config (last pass,
// 1632us / absmax 3.90625e-3): PROJ4 back to (2,1) (split input x single
// weight). Round-16's input-lo trim failed at 3.7e-2 (input feeds th,ph,rh,ps
// multiplicatively -> 8x my error estimate). Keep only the numerics-neutral
// stride-9 NPART fix. This is the finalization candidate.

#define B_ 8
#define N_ 1024
#define D_ 512
#define L_ 4

typedef short s8v __attribute__((ext_vector_type(8)));
typedef short s4v __attribute__((ext_vector_type(4)));
typedef float f4v __attribute__((ext_vector_type(4)));

__device__ __forceinline__ unsigned short f2b(float f) {
  unsigned u = __builtin_bit_cast(unsigned, f);
  u += 0x7FFFu + ((u >> 16) & 1u);          // round-to-nearest-even
  return (unsigned short)(u >> 16);
}
__device__ __forceinline__ float b2f(short s) {
  unsigned u = ((unsigned)(unsigned short)s) << 16;
  return __builtin_bit_cast(float, u);
}

__device__ __forceinline__ void glds16(const short* g, short* l) {
  __builtin_amdgcn_global_load_lds(
      (const __attribute__((address_space(1))) void*)g,
      (__attribute__((address_space(3))) void*)l, 16, 0, 0);
}

enum {
  EPI_PROJ4 = 0,   // seg even: split(acc+bias)->C0/C1; seg odd: TR(acc+bias)->C0
  EPI_PROJ3,       // seg 0,1: bf16(acc+bias)->C0; seg 2: TR->C0
  EPI_B16_SCALE,   // C0 bf16 = acc*alpha
  EPI_ACC2,        // seg s: C0[s] f32 += acc   (z-batched)
  EPI_ACC2_ST,     // seg s: C0[s] f32 = acc    (layer 0)
  EPI_F32_ACC,     // C0[0] f32 += acc          (z-batched)
  EPI_F32_ST,      // C0[0] f32 = acc           (layer 0)
  EPI_F32_BIAS_R,  // C0 f32 = acc+bias+R (+ fused norm partials -> NP)
  EPI_SPLIT_BIAS,  // C0 hi, C1 lo of acc+bias
  EPI_BOTH_LEAKY,  // C0 bf16 AND C1 f32 = leaky(acc+bias)
  EPI_LEAKY_R,     // C0 f32 = leaky(acc+bias)+R (+ fused norm partials -> NP)
  EPI_ACC2_SPLIT,  // seg s: t=(C0[s]+acc)*alpha; hi->C1[s], lo->C1[2+s]
  EPI_ACC_SPLIT    // t=(C0[0]+acc)*alpha; hi->C1[0], lo->C1[1] (z-batched)
};

struct GArgs {
  const short* Ah[4]; const short* Al[4];
  const short* Bh[4]; const short* Bl[4];
  long sA, sB;
  void* C0[4]; void* C1[4];
  long sC;
  const float* bias[4];
  const void* Rv; const void* Rv2;
  float* NP;                      // fused norm partials (F32_BIAS_R/LEAKY_R)
  float alpha;
  int Nn, K;
};

// C = (ΣA_c)(ΣB_c)^T, bf16 comps, f32 accum; <2,2> drops Al*Bl.
// 128x128 tile, 4 waves, global_load_lds(16B) + both-sides XOR swizzle.
// DB=1: double-buffered staging, counted vmcnt. XCD-chunked y-fastest blocks.
template<int AS, int BS, int EPI, int DB>
__global__ __launch_bounds__(256) void gemm_k(GArgs g) {
  constexpr int TILE = (AS + BS) * 4096;        // shorts per staging buffer
  __shared__ short smem[TILE * (DB ? 2 : 1)];
  constexpr bool SEG = (EPI == EPI_PROJ4 || EPI == EPI_PROJ3 ||
                        EPI == EPI_ACC2 || EPI == EPI_ACC2_ST ||
                        EPI == EPI_ACC2_SPLIT);
  constexpr bool LDSOUT = (EPI == EPI_PROJ4 || EPI == EPI_PROJ3 ||
                           EPI == EPI_B16_SCALE || EPI == EPI_SPLIT_BIAS ||
                           EPI == EPI_BOTH_LEAKY || EPI == EPI_ACC2_SPLIT ||
                           EPI == EPI_ACC_SPLIT);
  constexpr int CC = (EPI == EPI_PROJ4 || EPI == EPI_SPLIT_BIAS ||
                      EPI == EPI_ACC2_SPLIT || EPI == EPI_ACC_SPLIT) ? 2 : 1;
  constexpr bool FITS = (TILE * (DB ? 2 : 1)) >= CC * 16384;  // full-tile epi
  constexpr bool NPART = (EPI == EPI_F32_BIAS_R || EPI == EPI_LEAKY_R);
  const int z = blockIdx.z;

  // ---- L2-locality swizzle (all grids have nwg % 8 == 0) ----
  const int GX = gridDim.x, GY = gridDim.y;
  const int nwg = GX * GY;
  const int orig = blockIdx.y * GX + blockIdx.x;
  const int wgid = (orig & 7) * (nwg >> 3) + (orig >> 3);
  const int bx = wgid / GY;
  const int by = wgid - bx * GY;
  const int tm = bx * 128;
  const int tn = by * 128;

  const int tid = threadIdx.x;
  const int lane = tid & 63;
  const int w = tid >> 6;
  const int wr = (w >> 1) * 64, wc = (w & 1) * 64;
  const int r16 = lane & 15, kg = lane >> 4;
  const int K = g.K;

  int seg = 0, tnl = tn;
  if constexpr (SEG) { seg = tn >> 9; tnl = tn & 511; }
  const short* Ah = g.Ah[seg];
  const short* Al = (AS == 2) ? g.Al[seg] : nullptr;
  const short* Bh = g.Bh[seg];
  const short* Bl = (BS == 2) ? g.Bl[seg] : nullptr;

  const int srow = lane >> 2;
  const int scol = ((lane & 3) ^ ((lane >> 3) & 3)) * 8;
  const short* gA[2]; const short* gB[2];
  gA[0] = Ah + (size_t)z * g.sA + (size_t)(tm + w * 16 + srow) * K + scol;
  if constexpr (AS == 2)
    gA[1] = Al + (size_t)z * g.sA + (size_t)(tm + w * 16 + srow) * K + scol;
  gB[0] = Bh + (size_t)z * g.sB + (size_t)(tnl + w * 16 + srow) * K + scol;
  if constexpr (BS == 2)
    gB[1] = Bl + (size_t)z * g.sB + (size_t)(tnl + w * 16 + srow) * K + scol;
  const size_t hoff = (size_t)64 * K;

  auto stage = [&](int k0, int buf) {
    short* base = smem + buf * TILE;
    #pragma unroll
    for (int c = 0; c < AS; c++) {
      glds16(gA[c] + k0, base + c * 4096 + (w * 16) * 32);
      glds16(gA[c] + hoff + k0, base + c * 4096 + (64 + w * 16) * 32);
    }
    #pragma unroll
    for (int c = 0; c < BS; c++) {
      glds16(gB[c] + k0, base + (AS + c) * 4096 + (w * 16) * 32);
      glds16(gB[c] + hoff + k0, base + (AS + c) * 4096 + (64 + w * 16) * 32);
    }
  };

  f4v acc[4][4];
  #pragma unroll
  for (int i = 0; i < 4; i++)
    #pragma unroll
    for (int j = 0; j < 4; j++) acc[i][j] = (f4v)0.f;

  const int rc = (kg ^ ((r16 >> 1) & 3)) * 8;

  auto compute = [&](int buf) {
    const short* base = smem + buf * TILE;
    s8v va[2][4], vb[2][4];
    #pragma unroll
    for (int c = 0; c < AS; c++)
      #pragma unroll
      for (int i = 0; i < 4; i++)
        va[c][i] = *(const s8v*)&base[c * 4096 + (wr + i * 16 + r16) * 32 + rc];
    #pragma unroll
    for (int c = 0; c < BS; c++)
      #pragma unroll
      for (int i = 0; i < 4; i++)
        vb[c][i] = *(const s8v*)&base[(AS + c) * 4096 + (wc + i * 16 + r16) * 32 + rc];
    #pragma unroll
    for (int ca = 0; ca < AS; ca++)
      #pragma unroll
      for (int cb = 0; cb < BS; cb++) {
        if (ca == 1 && cb == 1) continue;   // drop lo*lo
        #pragma unroll
        for (int mi = 0; mi < 4; mi++)
          #pragma unroll
          for (int ni = 0; ni < 4; ni++)
            acc[mi][ni] = __builtin_amdgcn_mfma_f32_16x16x32_bf16(
                va[ca][mi], vb[cb][ni], acc[mi][ni], 0, 0, 0);
      }
  };

  const int nt = K >> 5;
  if constexpr (DB) {
    constexpr int NLD = (AS + BS) * 2;        // vmcnt events per stage
    stage(0, 0);
    int buf = 0;
    for (int t = 0; t < nt; t++) {
      if (t + 1 < nt) {
        stage((t + 1) * 32, buf ^ 1);
        if constexpr (NLD == 8)      asm volatile("s_waitcnt vmcnt(8)" ::: "memory");
        else if constexpr (NLD == 6) asm volatile("s_waitcnt vmcnt(6)" ::: "memory");
        else                         asm volatile("s_waitcnt vmcnt(4)" ::: "memory");
      } else {
        asm volatile("s_waitcnt vmcnt(0)" ::: "memory");
      }
      __builtin_amdgcn_sched_barrier(0);
      __builtin_amdgcn_s_barrier();
      compute(buf);
      __builtin_amdgcn_s_barrier();
      buf ^= 1;
    }
  } else {
    for (int t = 0; t < nt; t++) {
      stage(t * 32, 0);
      __syncthreads();
      compute(0);
      __syncthreads();
    }
  }

  short* C0s = (short*)g.C0[seg];  float* C0f = (float*)g.C0[seg];
  short* C1s = (short*)g.C1[seg];  float* C1f = (float*)g.C1[seg];
  const float* biasp = g.bias[seg];
  const int NnL = g.Nn;

  if constexpr (LDSOUT) {
    bool tr = false;
    if constexpr (EPI == EPI_PROJ4) tr = (seg & 1);
    if constexpr (EPI == EPI_PROJ3) tr = (seg == 2);
    if (tr) {
      // transposed write (s4v along n, 8B-coalesced)
      #pragma unroll
      for (int mi = 0; mi < 4; mi++) {
        #pragma unroll
        for (int ni = 0; ni < 4; ni++) {
          const int colL = tnl + wc + ni * 16 + r16;
          const int grow0 = tm + wr + mi * 16 + kg * 4;
          const float bv = biasp[colL];
          s4v o;
          #pragma unroll
          for (int r = 0; r < 4; r++) o[r] = (short)f2b(acc[mi][ni][r] + bv);
          const int b = grow0 >> 10, n = grow0 & 1023;
          *(s4v*)&C0s[((size_t)b * 512 + colL) * 1024 + n] = o;
        }
      }
    } else {
      short* D0 = nullptr; short* D1 = nullptr;
      if constexpr (EPI == EPI_PROJ4 || EPI == EPI_PROJ3) {
        D0 = C0s; D1 = C1s;
      } else if constexpr (EPI == EPI_SPLIT_BIAS) {
        D0 = C0s + (size_t)z * g.sC; D1 = C1s + (size_t)z * g.sC;
      } else if constexpr (EPI == EPI_B16_SCALE || EPI == EPI_BOTH_LEAKY) {
        D0 = C0s + (size_t)z * g.sC;
      } else if constexpr (EPI == EPI_ACC2_SPLIT) {
        D0 = (short*)g.C1[seg] + (size_t)z * g.sC;
        D1 = (short*)g.C1[2 + seg] + (size_t)z * g.sC;
      } else { // EPI_ACC_SPLIT
        D0 = (short*)g.C1[0] + (size_t)z * g.sC;
        D1 = (short*)g.C1[1] + (size_t)z * g.sC;
      }
      auto elem = [&](int mi, int ni, int r, float bv) -> float {
        const int grow = tm + wr + mi * 16 + kg * 4 + r;
        const int colL = tnl + wc + ni * 16 + r16;
        const float v = acc[mi][ni][r];
        float t;
        if constexpr (EPI == EPI_B16_SCALE)
          t = v * g.alpha;
        else if constexpr (EPI == EPI_ACC2_SPLIT || EPI == EPI_ACC_SPLIT)
          t = (C0f[(size_t)z * g.sC + (size_t)grow * NnL + colL] + v) * g.alpha;
        else if constexpr (EPI == EPI_BOTH_LEAKY) {
          t = v + bv; t = (t >= 0.f) ? t : 0.01f * t;
          C1f[(size_t)z * g.sC + (size_t)grow * NnL + colL] = t;
        } else
          t = v + bv;
        return t;
      };
      if constexpr (FITS) {
        // ---- full-tile epilogue: ONE barrier ----
        #pragma unroll
        for (int mi = 0; mi < 4; mi++) {
          #pragma unroll
          for (int ni = 0; ni < 4; ni++) {
            const int lcol = wc + ni * 16 + r16;
            float bv = 0.f;
            if constexpr (EPI == EPI_PROJ4 || EPI == EPI_PROJ3 ||
                          EPI == EPI_SPLIT_BIAS || EPI == EPI_BOTH_LEAKY)
              bv = biasp[tnl + lcol];
            #pragma unroll
            for (int r = 0; r < 4; r++) {
              const float t = elem(mi, ni, r, bv);
              const int lrow = wr + mi * 16 + kg * 4 + r;     // 0..127
              const int sw = ((lrow >> 2) & 3) << 4;          // bank swizzle
              const int li = lrow * 128 + (lcol ^ sw);
              const short h = (short)f2b(t);
              smem[li] = h;
              if constexpr (CC == 2) smem[16384 + li] = (short)f2b(t - b2f(h));
            }
          }
        }
        __syncthreads();
        #pragma unroll
        for (int c2 = 0; c2 < CC; c2++) {
          short* D = c2 ? D1 : D0;
          #pragma unroll
          for (int it = 0; it < 8; it++) {
            const int e = (tid + it * 256) * 8;
            const int lrow2 = e >> 7, col = e & 127;
            const int sw2 = ((lrow2 >> 2) & 3) << 4;
            *(s8v*)&D[(size_t)(tm + lrow2) * NnL + tnl + col] =
                *(const s8v*)&smem[c2 * 16384 + (lrow2 << 7) + (col ^ sw2)];
          }
        }
      } else {
        // ---- per-mi strip epilogue (small-LDS CC=2 cases) ----
        for (int mi = 0; mi < 4; mi++) {
          #pragma unroll
          for (int ni = 0; ni < 4; ni++) {
            const int lcol = wc + ni * 16 + r16;
            float bv = 0.f;
            if constexpr (EPI == EPI_PROJ4 || EPI == EPI_PROJ3 ||
                          EPI == EPI_SPLIT_BIAS || EPI == EPI_BOTH_LEAKY)
              bv = biasp[tnl + lcol];
            #pragma unroll
            for (int r = 0; r < 4; r++) {
              const float t = elem(mi, ni, r, bv);
              const int lrow = (w >> 1) * 16 + kg * 4 + r;
              const int sw = ((lrow >> 2) & 3) << 4;
              const int li = lrow * 128 + (lcol ^ sw);
              const short h = (short)f2b(t);
              smem[li] = h;
              if constexpr (CC == 2) smem[4096 + li] = (short)f2b(t - b2f(h));
            }
          }
          __syncthreads();
          #pragma unroll
          for (int c2 = 0; c2 < CC; c2++) {
            short* D = c2 ? D1 : D0;
            #pragma unroll
            for (int half = 0; half < 2; half++) {
              const int e = (tid + half * 256) * 8;
              const int lrow2 = e >> 7, col = e & 127;
              const int sw2 = ((lrow2 >> 2) & 3) << 4;
              const int grow = tm + (lrow2 >> 4) * 64 + mi * 16 + (lrow2 & 15);
              *(s8v*)&D[(size_t)grow * NnL + tnl + col] =
                  *(const s8v*)&smem[c2 * 4096 + (lrow2 << 7) + (col ^ sw2)];
            }
          }
          __syncthreads();
        }
      }
    }
  } else {
    // direct f32 epilogues (coalesced 64B/group); NPART fuses norm partials
    float ss[4] = {0.f, 0.f, 0.f, 0.f};
    #pragma unroll
    for (int mi = 0; mi < 4; mi++) {
      #pragma unroll
      for (int ni = 0; ni < 4; ni++) {
        const int colL = tnl + wc + ni * 16 + r16;
        const int grow0 = tm + wr + mi * 16 + kg * 4;
        float bv = 0.f;
        if constexpr (EPI == EPI_F32_BIAS_R || EPI == EPI_LEAKY_R)
          bv = biasp[colL];
        #pragma unroll
        for (int r = 0; r < 4; r++) {
          const size_t lidx = (size_t)(grow0 + r) * NnL + colL;
          const size_t idx = (size_t)z * g.sC + lidx;
          const float v = acc[mi][ni][r];
          if constexpr (EPI == EPI_ACC2) {
            C0f[(size_t)z * g.sC + (size_t)(grow0 + r) * 512 + colL] += v;
          } else if constexpr (EPI == EPI_ACC2_ST) {
            C0f[(size_t)z * g.sC + (size_t)(grow0 + r) * 512 + colL] = v;
          } else if constexpr (EPI == EPI_F32_ACC) {
            C0f[idx] += v;
          } else if constexpr (EPI == EPI_F32_ST) {
            C0f[idx] = v;
          } else if constexpr (EPI == EPI_F32_BIAS_R) {
            const float* Rf = (const float*)(z == 0 ? g.Rv : g.Rv2);
            const float t = v + bv + Rf[lidx];
            C0f[idx] = t;
            ss[ni] += t * t;
          } else { // EPI_LEAKY_R
            float t = v + bv; t = (t >= 0.f) ? t : 0.01f * t;
            t += ((const float*)g.Rv)[idx];
            C0f[idx] = t;
            ss[ni] += t * t;
          }
        }
      }
    }
    if constexpr (NPART) {
      // reduce 8 contributors per column via LDS (stride 9: conflict-free)
      float* sred = (float*)smem;                  // 128 cols x 9 slots
      const int slot = (w >> 1) * 4 + kg;          // 0..7
      __syncthreads();                             // smem free after K-loop
      #pragma unroll
      for (int ni = 0; ni < 4; ni++)
        sred[(wc + ni * 16 + r16) * 9 + slot] = ss[ni];
      __syncthreads();
      if (tid < 128) {
        float s = 0.f;
        #pragma unroll
        for (int j = 0; j < 8; j++) s += sred[tid * 9 + j];
        g.NP[(size_t)(z * GX + bx) * 512 + tnl + tid] = s;
      }
    }
  }
}

// ---- merged weight conversion: z-indexed table of DxD transposes ----
struct WcvtArgs {
  const float* src[32];
  short* hi[32];
  short* lo[32];      // nullptr -> single bf16
  int n;
};
__global__ __launch_bounds__(256) void wt_cvt_all(WcvtArgs a) {
  __shared__ float t[32][33];
  const int zi = blockIdx.z;
  const int bx = blockIdx.x * 32, by = blockIdx.y * 32;
  const int tx = threadIdx.x, ty = threadIdx.y;
  const float* src = a.src[zi];
  #pragma unroll
  for (int k = 0; k < 4; k++)
    t[ty + 8 * k][tx] = src[(size_t)(by + ty + 8 * k) * D_ + bx + tx];
  __syncthreads();
  short* hi = a.hi[zi];
  short* lo = a.lo[zi];
  if (lo) {
    #pragma unroll
    for (int k = 0; k < 4; k++) {
      const size_t o = (size_t)(bx + ty + 8 * k) * D_ + by + tx;
      float v = t[tx][ty + 8 * k];
      short h = (short)f2b(v);
      hi[o] = h;
      lo[o] = (short)f2b(v - b2f(h));
    }
  } else {
    #pragma unroll
    for (int k = 0; k < 4; k++)
      hi[(size_t)(bx + ty + 8 * k) * D_ + by + tx] =
          (short)f2b(t[tx][ty + 8 * k]);
  }
}

// f32 * scale -> hi bf16 + lo bf16
__global__ __launch_bounds__(256) void split_f32(const float* __restrict__ src,
                                                 short* __restrict__ hi,
                                                 short* __restrict__ lo, float scale) {
  const size_t i = ((size_t)blockIdx.x * 256 + threadIdx.x) * 4;
  f4v v = *(const f4v*)(src + i);
  s4v h, l;
  #pragma unroll
  for (int j = 0; j < 4; j++) {
    float t = v[j] * scale;
    h[j] = (short)f2b(t);
    l[j] = (short)f2b(t - b2f(h[j]));
  }
  *(s4v*)(hi + i) = h;
  *(s4v*)(lo + i) = l;
}

// sum = a + b (f32) elementwise; write bf16 + f32 (outf may alias a)
__global__ __launch_bounds__(256) void add_both(const float* __restrict__ a,
                                                const float* __restrict__ b,
                                                short* __restrict__ outb,
                                                float* outf) {
  const size_t i = ((size_t)blockIdx.x * 256 + threadIdx.x) * 4;
  f4v av = *(const f4v*)(a + i);
  f4v bv = *(const f4v*)(b + i);
  f4v s; s4v o;
  #pragma unroll
  for (int j = 0; j < 4; j++) { s[j] = av[j] + bv[j]; o[j] = (short)f2b(s[j]); }
  *(f4v*)(outf + i) = s;
  *(s4v*)(outb + i) = o;
}

// in-place softmax over bf16 rows of 1024; one wave per row, shuffle reduce
__global__ __launch_bounds__(256) void softmax_rows_b16(short* __restrict__ p) {
  const int row = blockIdx.x * 4 + (threadIdx.x >> 6);
  const int lane = threadIdx.x & 63;
  short* rp = p + (size_t)row * 1024 + lane * 16;
  s8v v0 = *(s8v*)rp, v1 = *(s8v*)(rp + 8);
  float f[16];
  #pragma unroll
  for (int j = 0; j < 8; j++) { f[j] = b2f(v0[j]); f[8 + j] = b2f(v1[j]); }
  float m = f[0];
  #pragma unroll
  for (int j = 1; j < 16; j++) m = fmaxf(m, f[j]);
  #pragma unroll
  for (int s = 32; s; s >>= 1) m = fmaxf(m, __shfl_xor(m, s, 64));
  float sum = 0.f;
  #pragma unroll
  for (int j = 0; j < 16; j++) { f[j] = __expf(f[j] - m); sum += f[j]; }
  #pragma unroll
  for (int s = 32; s; s >>= 1) sum += __shfl_xor(sum, s, 64);
  const float inv = 1.f / sum;
  #pragma unroll
  for (int j = 0; j < 8; j++) {
    v0[j] = (short)f2b(f[j] * inv);
    v1[j] = (short)f2b(f[8 + j] * inv);
  }
  *(s8v*)rp = v0; *(s8v*)(rp + 8) = v1;
}

// norm_inv from fused tile partials: part[tile][512], 8 tiles per batch row
__global__ __launch_bounds__(256) void norm_inv(const float* __restrict__ part,
                                                float* __restrict__ inv, int NB) {
  const int i = blockIdx.x * 256 + threadIdx.x;   // b*512 + d
  const int b = i >> 9, d = i & 511;
  float ss = 0.f;
  #pragma unroll
  for (int t = 0; t < 8; t++)
    ss += part[(size_t)(b * 8 + t) * 512 + d];
  inv[i] = 1.f / fmaxf(sqrtf(ss), 1e-12f);
}
__global__ __launch_bounds__(256) void norm_scale(const float* __restrict__ t,
                                                  const float* __restrict__ inv,
                                                  short* __restrict__ outh,
                                                  short* __restrict__ outl,
                                                  float* __restrict__ outf) {
  const size_t i = ((size_t)blockIdx.x * 256 + threadIdx.x) * 4;
  const int b = (int)(i >> 19);        // N_*D_ = 2^19
  const int d = (int)(i & (D_ - 1));
  f4v v = *(const f4v*)(t + i);
  f4v w = *(const f4v*)(inv + (size_t)b * D_ + d);
  f4v o; s4v oh, ol;
  #pragma unroll
  for (int j = 0; j < 4; j++) {
    o[j] = v[j] * w[j];
    oh[j] = (short)f2b(o[j]);
    ol[j] = (short)f2b(o[j] - b2f(oh[j]));
  }
  *(f4v*)(outf + i) = o;
  *(s4v*)(outh + i) = oh;
  *(s4v*)(outl + i) = ol;
}

extern "C" void kernel_launch(void* const* d_in, const int* in_sizes, int n_in,
                              void* d_out, int out_size, void* d_ws, size_t ws_size,
                              hipStream_t stream) {
  (void)in_sizes; (void)n_in; (void)out_size; (void)ws_size;
  const float* in1f = (const float*)d_in[0];
  const float* in2f = (const float*)d_in[1];

  const size_t SB = (size_t)B_ * N_ * D_ * 2;      // 8 MB
  const size_t SF = (size_t)B_ * N_ * D_ * 4;      // 16 MB
  const size_t WL = (size_t)L_ * D_ * D_ * 2;
  const size_t W1 = (size_t)D_ * D_ * 2;
  const size_t WD = (size_t)D_ * D_;               // elems per DxD slice
  const long SBel = (long)B_ * N_ * D_;            // 4194304 elems
  const long sAct = (long)N_ * D_;
  const long sAff = (long)N_ * N_;

  char* ws = (char*)d_ws;
  size_t off = 0;
  auto alloc = [&](size_t bytes) -> char* {
    char* p = ws + off;
    off += (bytes + 255) & ~(size_t)255;
    return p;
  };

  // ---- weight region; stage-1 proj weights SINGLE bf16 ----
  char* wreg = alloc(8 * WL + 6 * W1);
  short* c_thT_h = (short*)(wreg);
  short* c_phT_h = (short*)(wreg + WL);
  short* c_rhT_h = (short*)(wreg + 2 * WL);
  short* c_psT_h = (short*)(wreg + 3 * WL);
  short* c_intT_h = (short*)(wreg + 8 * WL);
  short* c_intT_l = (short*)(wreg + 8 * WL + W1);
  short* c_f1T_h  = (short*)(wreg + 8 * WL + 2 * W1);
  short* c_f1T_l  = (short*)(wreg + 8 * WL + 3 * W1);
  short* c_f2T_h  = (short*)(wreg + 8 * WL + 4 * W1);
  short* c_f2T_l  = (short*)(wreg + 8 * WL + 5 * W1);
  short* a1_thT = (short*)(wreg);
  short* a1_phT = (short*)(wreg + WL);
  short* a1_rhT = (short*)(wreg + 2 * WL);
  short* a2_thT = (short*)(wreg + 3 * WL);
  short* a2_phT = (short*)(wreg + 4 * WL);
  short* a2_rhT = (short*)(wreg + 5 * WL);
  char*  aw = wreg + 6 * WL;
  short* a1_intT_h = (short*)(aw);
  short* a1_intT_l = (short*)(aw + W1);
  short* a1_f1T_h  = (short*)(aw + 2 * W1);
  short* a1_f1T_l  = (short*)(aw + 3 * W1);
  short* a1_f2T_h  = (short*)(aw + 4 * W1);
  short* a1_f2T_l  = (short*)(aw + 5 * W1);
  short* a2_intT_h = (short*)(aw + 6 * W1);
  short* a2_intT_l = (short*)(aw + 7 * W1);
  short* a2_f1T_h  = (short*)(aw + 8 * W1);
  short* a2_f1T_l  = (short*)(aw + 9 * W1);
  short* a2_f2T_h  = (short*)(aw + 10 * W1);
  short* a2_f2T_l  = (short*)(aw + 11 * W1);

  // ---- pair-contiguous activation regions (2*SB each = 16 MB) ----
  short* in12h = (short*)alloc(2 * SB);   // in1h|in2h -> feed12b -> sumb
  short* in12l = (short*)alloc(2 * SB);   // in1l|in2l -> resh
  short* bufA  = (short*)alloc(2 * SB);   // thh|thl -> inth -> hidh
  short* bufB  = (short*)alloc(2 * SB);   // phh|phl -> intl -> hidl
  short* bufC  = (short*)alloc(2 * SB);   // rhT|psT -> resl
  char*  affU  = alloc((size_t)32 * 1024 * 1024);
  float* accR  = (float*)alloc(2 * SF);   // acc1|acc2 / acc16 / tmpf
  float* feedfR = (float*)alloc(2 * SF);  // feed12f -> self12f -> sumf
  float* npart = (float*)alloc((size_t)128 * 512 * 4);   // tile partials
  float* ninv  = (float*)alloc((size_t)16 * D_ * 4);
  // total ≈ 196 MB (< proven 217)

  short* in1h = in12h;        short* in2h = in12h + SBel;
  short* in1l = in12l;        short* in2l = in12l + SBel;
  short* thh = bufA;          short* thl = bufA + SBel;
  short* phh = bufB;          short* phl = bufB + SBel;
  short* rhT = bufC;          short* psT = bufC + SBel;
  short* affh = (short*)affU;                   // [0,16 MB)
  short* aff16 = (short*)affU;                  // 32 MB bf16 batch-16 logits
  float* resfP = (float*)affU;                  // 32 MB f32 res (affs dead)
  float* acc1 = accR;         float* acc2 = accR + SBel;

  const float scl = 0.04419417382415922f;   // 512^-0.5
  dim3 tb(32, 8);
  const int GE = (B_ * N_ * D_) / (4 * 256);     // 4096
  #define F32P(i) ((const float*)d_in[i])

  auto GA = [&]() { GArgs a; __builtin_memset(&a, 0, sizeof(a)); return a; };
  auto normalize = [&](const float* src, int NB, short* outh, short* outl, float* outf) {
    norm_inv<<<(NB * D_) / 256, 256, 0, stream>>>(npart, ninv, NB);
    norm_scale<<<NB * 512, 256, 0, stream>>>(src, ninv, outh, outl, outf);
  };

  // ---- stage-1 weights: proj single bf16 + int/f1/f2 split ----
  {
    WcvtArgs wa; __builtin_memset(&wa, 0, sizeof(wa));
    int n = 0;
    auto addS = [&](const float* s, short* h, int nl) {
      for (int i = 0; i < nl; i++) {
        wa.src[n] = s + i * WD; wa.hi[n] = h + i * WD; wa.lo[n] = nullptr; n++;
      }
    };
    auto add2 = [&](const float* s, short* h, short* l) {
      wa.src[n] = s; wa.hi[n] = h; wa.lo[n] = l; n++;
    };
    addS(F32P(2),  c_thT_h, L_);
    addS(F32P(4),  c_phT_h, L_);
    addS(F32P(6),  c_rhT_h, L_);
    addS(F32P(8),  c_psT_h, L_);
    add2(F32P(10), c_intT_h, c_intT_l);
    add2(F32P(12), c_f1T_h, c_f1T_l);
    add2(F32P(14), c_f2T_h, c_f2T_l);
    wa.n = n;
    wt_cvt_all<<<dim3(16, 16, n), tb, 0, stream>>>(wa);
  }
  split_f32<<<GE, 256, 0, stream>>>(in1f, in1h, in1l, 1.0f);
  split_f32<<<GE, 256, 0, stream>>>(in2f, in2h, in2l, 1.0f);

  // ---- stage 1: (2,1) proj -> bf16 P -> (1,1) applies ----
  for (int i = 0; i < L_; i++) {
    const size_t wo = (size_t)i * D_ * D_;
    const size_t bo = (size_t)i * D_;
    { GArgs a = GA();
      a.Ah[0] = in1h; a.Ah[1] = in1h; a.Ah[2] = in2h; a.Ah[3] = in2h;
      a.Al[0] = in1l; a.Al[1] = in1l; a.Al[2] = in2l; a.Al[3] = in2l;
      a.Bh[0] = c_thT_h + wo; a.Bh[1] = c_rhT_h + wo;
      a.Bh[2] = c_phT_h + wo; a.Bh[3] = c_psT_h + wo;
      a.C0[0] = thh; a.C0[1] = rhT; a.C0[2] = phh; a.C0[3] = psT;
      a.C1[0] = thl; a.C1[2] = phl;
      a.bias[0] = F32P(3) + bo; a.bias[1] = F32P(7) + bo;
      a.bias[2] = F32P(5) + bo; a.bias[3] = F32P(9) + bo;
      a.Nn = 512; a.K = 512;
      gemm_k<2,1,EPI_PROJ4,1><<<dim3(64,16,1),256,0,stream>>>(a); }
    { GArgs a = GA();
      a.Ah[0] = thh; a.Al[0] = thl; a.sA = sAct;
      a.Bh[0] = phh; a.Bl[0] = phl; a.sB = sAct;
      a.C0[0] = affh; a.sC = sAff;
      a.alpha = scl; a.Nn = 1024; a.K = 512;
      gemm_k<2,2,EPI_B16_SCALE,1><<<dim3(8,8,B_),256,0,stream>>>(a); }
    { GArgs a = GA();
      a.Ah[0] = affh; a.Ah[1] = affh; a.sA = sAff;
      a.Bh[0] = rhT; a.Bh[1] = psT; a.sB = sAct;
      a.C0[0] = acc1; a.C0[1] = acc2; a.sC = sAct;
      a.Nn = 512; a.K = 1024;
      if (i == 0) {
        gemm_k<1,1,EPI_ACC2_ST,1><<<dim3(8,8,B_),256,0,stream>>>(a);
      } else if (i < L_ - 1) {
        gemm_k<1,1,EPI_ACC2,1><<<dim3(8,8,B_),256,0,stream>>>(a);
      } else {
        a.C1[0] = bufA; a.C1[1] = bufA + SBel;   // inth (stream1|stream2)
        a.C1[2] = bufB; a.C1[3] = bufB + SBel;   // intl
        a.alpha = 0.25f;
        gemm_k<1,1,EPI_ACC2_SPLIT,1><<<dim3(8,8,B_),256,0,stream>>>(a);
      } }
  }

  // ---- stage-1 epilogue, both streams batched (z=2 / M=16384) ----
  { GArgs a = GA();
    a.Ah[0] = bufA; a.Al[0] = bufB; a.sA = SBel;
    a.Bh[0] = c_intT_h; a.Bl[0] = c_intT_l;
    a.C0[0] = accR; a.sC = SBel;
    a.bias[0] = F32P(11); a.Rv = in1f; a.Rv2 = in2f; a.NP = npart;
    a.Nn = 512; a.K = 512;
    gemm_k<2,2,EPI_F32_BIAS_R,1><<<dim3(64,4,2),256,0,stream>>>(a); }
  normalize(accR, 16, in12l, bufA, resfP);       // resh|resl (resf scratch)
  { GArgs a = GA();
    a.Ah[0] = in12l; a.Al[0] = bufA;
    a.Bh[0] = c_f1T_h; a.Bl[0] = c_f1T_l;
    a.C0[0] = bufB; a.C1[0] = bufC;              // hidh|hidl
    a.bias[0] = F32P(13); a.Nn = 512; a.K = 512;
    gemm_k<2,2,EPI_SPLIT_BIAS,1><<<dim3(128,4,1),256,0,stream>>>(a); }
  { GArgs a = GA();
    a.Ah[0] = bufB; a.Al[0] = bufC;
    a.Bh[0] = c_f2T_h; a.Bl[0] = c_f2T_l;
    a.C0[0] = in12h; a.C1[0] = feedfR;           // feed12b | feed12f
    a.bias[0] = F32P(15); a.Nn = 512; a.K = 512;
    gemm_k<2,2,EPI_BOTH_LEAKY,1><<<dim3(128,4,1),256,0,stream>>>(a); }

  // ---- a1/a2 weights: ONE merged dispatch ----
  {
    WcvtArgs wa; __builtin_memset(&wa, 0, sizeof(wa));
    int n = 0;
    auto addS = [&](const float* s, short* h, int nl) {
      for (int i = 0; i < nl; i++) {
        wa.src[n] = s + i * WD; wa.hi[n] = h + i * WD; wa.lo[n] = nullptr; n++;
      }
    };
    auto add2 = [&](const float* s, short* h, short* l) {
      wa.src[n] = s; wa.hi[n] = h; wa.lo[n] = l; n++;
    };
    addS(F32P(16), a1_thT, L_);
    addS(F32P(18), a1_phT, L_);
    addS(F32P(20), a1_rhT, L_);
    addS(F32P(28), a2_thT, L_);
    addS(F32P(30), a2_phT, L_);
    addS(F32P(32), a2_rhT, L_);
    add2(F32P(22), a1_intT_h, a1_intT_l);
    add2(F32P(24), a1_f1T_h, a1_f1T_l);
    add2(F32P(26), a1_f2T_h, a1_f2T_l);
    add2(F32P(34), a2_intT_h, a2_intT_l);
    add2(F32P(36), a2_f1T_h, a2_f1T_l);
    add2(F32P(38), a2_f2T_h, a2_f2T_l);
    wa.n = n;                                    // 30 slices
    wt_cvt_all<<<dim3(16, 16, n), tb, 0, stream>>>(wa);
  }

  // ---- generic agi chain ----
  auto agi = [&](int NZ, const short* xb, const float* xf,
                 const short* thT, const float* thB,
                 const short* phT, const float* phB,
                 const short* rhT_, const float* rhB,
                 const short* inTh, const short* inTl, const float* inB,
                 const short* f1Th, const short* f1Tl, const float* f1B,
                 const short* f2Th, const short* f2Tl, const float* f2B,
                 float* outf) {
    const int MB = NZ / B_;                  // 2 or 1 (stream multiplier)
    for (int i = 0; i < L_; i++) {
      const size_t wo = (size_t)i * D_ * D_;
      const size_t bo = (size_t)i * D_;
      { GArgs a = GA();
        a.Ah[0] = xb; a.Ah[1] = xb; a.Ah[2] = xb;
        a.Bh[0] = thT + wo; a.Bh[1] = phT + wo; a.Bh[2] = rhT_ + wo;
        a.C0[0] = bufA; a.C0[1] = bufB; a.C0[2] = bufC;
        a.bias[0] = thB + bo; a.bias[1] = phB + bo; a.bias[2] = rhB + bo;
        a.Nn = 512; a.K = 512;
        gemm_k<1,1,EPI_PROJ3,1><<<dim3(64*MB,12,1),256,0,stream>>>(a); }
      { GArgs a = GA();
        a.Ah[0] = bufA; a.sA = sAct; a.Bh[0] = bufB; a.sB = sAct;
        a.C0[0] = aff16; a.sC = sAff; a.alpha = scl; a.Nn = 1024; a.K = 512;
        gemm_k<1,1,EPI_B16_SCALE,1><<<dim3(8,8,NZ),256,0,stream>>>(a); }
      softmax_rows_b16<<<NZ * 256, 256, 0, stream>>>(aff16);
      { GArgs a = GA();
        a.Ah[0] = aff16; a.sA = sAff; a.Bh[0] = bufC; a.sB = sAct;
        a.C0[0] = accR; a.sC = sAct; a.Nn = 512; a.K = 1024;
        if (i == 0) {
          gemm_k<1,1,EPI_F32_ST,1><<<dim3(8,4,NZ),256,0,stream>>>(a);
        } else if (i < L_ - 1) {
          gemm_k<1,1,EPI_F32_ACC,1><<<dim3(8,4,NZ),256,0,stream>>>(a);
        } else {
          a.C1[0] = bufA; a.C1[1] = bufB; a.alpha = 0.25f;
          gemm_k<1,1,EPI_ACC_SPLIT,1><<<dim3(8,4,NZ),256,0,stream>>>(a);
        } }
    }
    { GArgs a = GA();
      a.Ah[0] = bufA; a.Al[0] = bufB;
      a.Bh[0] = inTh; a.Bl[0] = inTl;
      a.C0[0] = accR; a.bias[0] = inB; a.Rv = xf; a.Rv2 = xf; a.NP = npart;
      a.Nn = 512; a.K = 512;
      gemm_k<2,2,EPI_F32_BIAS_R,1><<<dim3(64*MB,4,1),256,0,stream>>>(a); }
    normalize(accR, NZ, in12l, bufC, resfP);     // resh|resl, resf -> affU
    { GArgs a = GA();
      a.Ah[0] = in12l; a.Al[0] = bufC;
      a.Bh[0] = f1Th; a.Bl[0] = f1Tl;
      a.C0[0] = bufA; a.C1[0] = bufB;            // hidh|hidl
      a.bias[0] = f1B; a.Nn = 512; a.K = 512;
      gemm_k<2,2,EPI_SPLIT_BIAS,1><<<dim3(64*MB,4,1),256,0,stream>>>(a); }
    { GArgs a = GA();
      a.Ah[0] = bufA; a.Al[0] = bufB;
      a.Bh[0] = f2Th; a.Bl[0] = f2Tl;
      a.C0[0] = accR; a.bias[0] = f2B; a.Rv = resfP; a.NP = npart;
      a.Nn = 512; a.K = 512;
      gemm_k<2,2,EPI_LEAKY_R,1><<<dim3(64*MB,4,1),256,0,stream>>>(a); }
    normalize(accR, NZ, bufA, bufB, outf);       // bf16 outs are scratch
  };

  // agi1 on feed1+feed2 as one batch-16 chain (shared AGI_1 weights)
  agi(16, in12h, feedfR,
      a1_thT, F32P(17), a1_phT, F32P(19), a1_rhT, F32P(21),
      a1_intT_h, a1_intT_l, F32P(23), a1_f1T_h, a1_f1T_l, F32P(25),
      a1_f2T_h, a1_f2T_l, F32P(27), feedfR);     // self12f -> feedfR

  add_both<<<GE, 256, 0, stream>>>(feedfR, feedfR + SBel, in12h, feedfR);

  agi(8, in12h, feedfR,
      a2_thT, F32P(29), a2_phT, F32P(31), a2_rhT, F32P(33),
      a2_intT_h, a2_intT_l, F32P(35), a2_f1T_h, a2_f1T_l, F32P(37),
      a2_f2T_h, a2_f2T_l, F32P(39), (float*)d_out);
}